// Round 10
// baseline (459.574 us; speedup 1.0000x reference)
//
#include <hip/hip_runtime.h>
#include <hip/hip_bf16.h>
#include <math.h>

#define BN 12
#define HG 28
#define WG 60
#define LL 1680      // HG*WG
#define CC 128
#define P2 20
#define HID 256
#define NPTS (BN * LL * P2)  // 403200
#define NPB 32               // points per block in gemm kernel (R10: 64->32 for occupancy)
#define NWG (NPTS / NPB)     // 12600
#define BPB (LL * P2 / NPB)  // 1050 blocks per bn

static constexpr size_t OUT_CAM_OFF = (size_t)BN * LL * P2 * CC;              // 51609600
static constexpr size_t OUT_PTS_OFF = OUT_CAM_OFF + (size_t)BN * LL * P2 * 2; // 52416000

typedef short v8s __attribute__((ext_vector_type(8)));
typedef float v4f __attribute__((ext_vector_type(4)));
typedef unsigned long long u64;

__device__ __forceinline__ unsigned short f2bf(float f) {
  unsigned x = __float_as_uint(f);
  unsigned r = (x + 0x7FFFu + ((x >> 16) & 1u)) >> 16;
  return (unsigned short)r;
}

// ---------------- prep: transpose img (BN,C,L)->(BN,L,C) f32  ||  pack W2 ----------------
// Validated R7/R8 form (f32 featT — R9's bf16 regressed, reverted).
__global__ __launch_bounds__(256) void prep_k(const float* __restrict__ img,
                                              float* __restrict__ featT,
                                              const float* __restrict__ W2,
                                              unsigned short* __restrict__ W2bf) {
  const int b = blockIdx.x;
  const int t = threadIdx.x;
  if (b < 648) {
    __shared__ float tile[64][65];
    const int bz = b / 54;         // bn
    const int rem = b - bz * 54;
    const int by = rem / 27;       // c-tile
    const int bx = rem - by * 27;  // l-tile
    const int c0 = by * 64;
    const int l0 = bx * 64;
    {
      const int lx = t & 63;
      const int cy = t >> 6;
#pragma unroll
      for (int i = 0; i < 64; i += 4) {
        const int c = c0 + cy + i;
        const int l = l0 + lx;
        float v = 0.f;
        if (l < LL) v = img[((size_t)bz * CC + c) * LL + l];
        tile[cy + i][lx] = v;
      }
    }
    __syncthreads();
    {
      const int cx = t & 63;
      const int ly = t >> 6;
#pragma unroll
      for (int i = 0; i < 64; i += 4) {
        const int l = l0 + ly + i;
        const int c = c0 + cx;
        if (l < LL) featT[((size_t)bz * LL + l) * CC + c] = tile[cx][ly + i];
      }
    }
  } else {
    const int u = (b - 648) * 256 + t;
    if (u < 4096) {
      const int lane = u & 63;
      const int ks = (u >> 6) & 7;
      const int cg = u >> 9;
      const int col = cg * 16 + (lane & 15);
      const int kb = ks * 32 + (lane >> 4) * 8;
      v8s r;
#pragma unroll
      for (int e = 0; e < 8; ++e) r[e] = (short)f2bf(W2[(size_t)(kb + e) * CC + col]);
      *(v8s*)(W2bf + (size_t)u * 8) = r;
    }
  }
}

// ---------------- kernel A: geometry -> cam/pts outputs ONLY ----------------
// Projection math FROZEN (passing R3/R5/R6/R7/R8/R9). cam = cx/homo amplifies contraction-
// order noise near the homo clamp ~1e6x; keep byte-identical, in its own kernel.
__global__ __launch_bounds__(256) void geom_k(const float* __restrict__ means3D,
                                              const float* __restrict__ dvec,
                                              const float* __restrict__ cov3D,
                                              const float* __restrict__ l2i,
                                              float* __restrict__ out) {
  const int pid = blockIdx.x * 256 + threadIdx.x;
  if (pid >= NPTS) return;
  const unsigned qg = (unsigned)pid / P2;
  const int p = pid - (int)qg * P2;
  const unsigned bn = qg / LL;

  const size_t base3 = (size_t)qg * 3;
  const float m0 = means3D[base3 + 0], m1 = means3D[base3 + 1], m2 = means3D[base3 + 2];
  const float d0 = dvec[base3 + 0], d1 = dvec[base3 + 1], d2 = dvec[base3 + 2];
  const float* cv = cov3D + (size_t)qg * 9;
  const float q = d0 * (cv[0] * d0 + cv[1] * d1 + cv[2] * d2) +
                  d1 * (cv[3] * d0 + cv[4] * d1 + cv[5] * d2) +
                  d2 * (cv[6] * d0 + cv[7] * d1 + cv[8] * d2);
  const float s = sqrtf(q);
  const int k = p >> 2, j = p & 3;
  const float a = (-1.5f + 0.75f * (float)k) * s;     // lin5[k]*sqrt(q)
  const float tt = -0.5f + (1.0f / 3.0f) * (float)j;  // linP[j]
  const float px = m0 + a * d0 + tt * d1;             // orth=(d1,-d0,0)
  const float py = m1 + a * d1 - tt * d0;
  const float pz = m2 + a * d2;
  const float* M = l2i + (size_t)bn * 16;
  const float cx = M[0] * px + M[1] * py + M[2] * pz + M[3];
  const float cy = M[4] * px + M[5] * py + M[6] * pz + M[7];
  const float cz = M[8] * px + M[9] * py + M[10] * pz + M[11];
  const float homo = fmaxf(cz, 1e-6f);
  const float u = cx / homo;
  const float v = cy / homo;

  *(float2*)(out + OUT_CAM_OFF + (size_t)pid * 2) = make_float2(u, v);
  float* ptso = out + OUT_PTS_OFF + (size_t)pid * 3;
  ptso[0] = px;
  ptso[1] = py;
  ptso[2] = pz;
}

// ---------------- kernel B: MLP via MFMA + bilinear gather + coalesced write ----------------
// R10 change vs validated R8: NPB 64->32 (one tile pair per block). LDS 35.3->17.8 KB,
// launch_bounds (256,6): occupancy 16 -> ~24 waves/CU to hide the gather/store latency.
// Per-point math and phase order byte-identical to R8.
__global__ __launch_bounds__(256, 6) void gemm_k(
    const float* __restrict__ featT,  // (BN,L,C)
    const float* __restrict__ W1,
    const float* __restrict__ b1,
    const unsigned short* __restrict__ W2bf,
    const float* __restrict__ b2,
    float* __restrict__ out) {
  const int tid = threadIdx.x;
  const int wgid = blockIdx.x;
  const int gp0 = wgid * NPB;
  const int bn = wgid / BPB;  // blocks never span bn

  __shared__ __align__(16) char sH[NPB * 512];
  __shared__ u64 sOff8[NPB];
  __shared__ float4 sWl[NPB];
  __shared__ float4 sPnl[NPB];

  const int wv = tid >> 6;
  const int lane = tid & 63;
  const int lrow = lane & 15;
  const int g = lane >> 4;

  // B-fragments for this wave's 32 channels (issued early; latency hides under staging)
  v8s fb0[8], fb1[8];
#pragma unroll
  for (int ks = 0; ks < 8; ++ks) {
    fb0[ks] = *(const v8s*)(W2bf + (size_t)(((wv * 2 + 0) * 8 + ks) * 64 + lane) * 8);
    fb1[ks] = *(const v8s*)(W2bf + (size_t)(((wv * 2 + 1) * 8 + ks) * 64 + lane) * 8);
  }

  // W1/b1 slice: loaded ONCE (loop-invariant per thread)
  const int h4 = (tid & 63) * 4;
  const int pw = tid >> 6;
  const float4 a0 = *(const float4*)(W1 + h4);
  const float4 a1 = *(const float4*)(W1 + HID + h4);
  const float4 a2 = *(const float4*)(W1 + 2 * HID + h4);
  const float4 bb = *(const float4*)(b1 + h4);

  // stage: read back cam/pts for this block's points, derive bilinear records + pn
  if (tid < NPB) {
    const int pid = gp0 + tid;
    const float2 cm = *(const float2*)(out + OUT_CAM_OFF + (size_t)pid * 2);
    const float u = cm.x, v = cm.y;
    const float* ptso = out + OUT_PTS_OFF + (size_t)pid * 3;
    const float px = ptso[0], py = ptso[1], pz = ptso[2];

    const float x = u * 0.125f - 0.5f;
    const float y = v * 0.125f - 0.5f;
    const float x0f = floorf(x), y0f = floorf(y);
    const float wx = x - x0f, wy = y - y0f;
    const bool vx0 = (x0f >= 0.f) && (x0f < (float)WG);
    const bool vx1 = (x0f + 1.f >= 0.f) && (x0f + 1.f < (float)WG);
    const bool vy0 = (y0f >= 0.f) && (y0f < (float)HG);
    const bool vy1 = (y0f + 1.f >= 0.f) && (y0f + 1.f < (float)HG);
    const unsigned ix0 = (unsigned)(int)fminf(fmaxf(x0f, 0.f), (float)(WG - 1));
    const unsigned ix1 = (unsigned)(int)fminf(fmaxf(x0f + 1.f, 0.f), (float)(WG - 1));
    const unsigned iy0 = (unsigned)(int)fminf(fmaxf(y0f, 0.f), (float)(HG - 1));
    const unsigned iy1 = (unsigned)(int)fminf(fmaxf(y0f + 1.f, 0.f), (float)(HG - 1));
    sOff8[tid] = (u64)(iy0 * WG + ix0) | ((u64)(iy0 * WG + ix1) << 16) |
                 ((u64)(iy1 * WG + ix0) << 32) | ((u64)(iy1 * WG + ix1) << 48);
    sWl[tid] = make_float4((vx0 && vy0) ? (1.f - wx) * (1.f - wy) : 0.f,
                           (vx1 && vy0) ? wx * (1.f - wy) : 0.f,
                           (vx0 && vy1) ? (1.f - wx) * wy : 0.f,
                           (vx1 && vy1) ? wx * wy : 0.f);
    sPnl[tid] = make_float4(fminf(fmaxf((px + 50.f) * 0.01f, 0.f), 1.f),
                            fminf(fmaxf((py + 50.f) * 0.01f, 0.f), 1.f),
                            fminf(fmaxf((pz + 4.f) * 0.125f, 0.f), 1.f), 0.f);
  }
  __syncthreads();

  // phase A: H[NPB][256] = relu(pn @ W1 + b1) -> bf16 LDS (swizzled), b64 writes
#pragma unroll
  for (int it = 0; it < NPB / 4; ++it) {
    const int p = it * 4 + pw;
    const float4 pn = sPnl[p];
    const float v0 = fmaxf(bb.x + pn.x * a0.x + pn.y * a1.x + pn.z * a2.x, 0.f);
    const float v1 = fmaxf(bb.y + pn.x * a0.y + pn.y * a1.y + pn.z * a2.y, 0.f);
    const float v2 = fmaxf(bb.z + pn.x * a0.z + pn.y * a1.z + pn.z * a2.z, 0.f);
    const float v3 = fmaxf(bb.w + pn.x * a0.w + pn.y * a1.w + pn.z * a2.w, 0.f);
    __hip_bfloat162 plo = __float22bfloat162_rn(make_float2(v0, v1));
    __hip_bfloat162 phi = __float22bfloat162_rn(make_float2(v2, v3));
    const unsigned ulo = *reinterpret_cast<const unsigned*>(&plo);
    const unsigned uhi = *reinterpret_cast<const unsigned*>(&phi);
    const u64 pk = (u64)ulo | ((u64)uhi << 32);
    *(u64*)(sH + p * 512 + (((unsigned)(h4 * 2)) ^ (((unsigned)(p & 7)) << 4))) = pk;
  }
  __syncthreads();

  const float* featc = featT + (size_t)bn * (LL * CC);

  // phase B + interleaved epilogue (one tile pair {0,1} when NPB=32):
  // MFMA both -> bar -> transpose both -> bar -> epilogue of these 32 points
#pragma unroll
  for (int pg2 = 0; pg2 < NPB / 32; ++pg2) {
    v4f acc[2][2];
#pragma unroll
    for (int i = 0; i < 2; ++i)
#pragma unroll
      for (int c = 0; c < 2; ++c) acc[i][c] = (v4f){0.f, 0.f, 0.f, 0.f};

#pragma unroll
    for (int pth = 0; pth < 2; ++pth) {
      const int pt = pg2 * 2 + pth;
      const int arow = pt * 16 + lrow;
      const unsigned swz = ((unsigned)(arow & 7)) << 4;
      v8s fa[8];
#pragma unroll
      for (int ks = 0; ks < 8; ++ks)
        fa[ks] = *(const v8s*)(sH + arow * 512 + (((unsigned)(ks * 64 + g * 16)) ^ swz));
#pragma unroll
      for (int ks = 0; ks < 8; ++ks)
        acc[pth][0] = __builtin_amdgcn_mfma_f32_16x16x32_bf16(fa[ks], fb0[ks], acc[pth][0], 0, 0, 0);
#pragma unroll
      for (int ks = 0; ks < 8; ++ks)
        acc[pth][1] = __builtin_amdgcn_mfma_f32_16x16x32_bf16(fa[ks], fb1[ks], acc[pth][1], 0, 0, 0);
    }
    __syncthreads();  // all waves done reading this pair's bf16 rows
#pragma unroll
    for (int pth = 0; pth < 2; ++pth) {
      const int pt = pg2 * 2 + pth;
#pragma unroll
      for (int r = 0; r < 4; ++r) {
        const int lp = pt * 16 + g * 4 + r;  // C/D: row=(lane>>4)*4+r, col=lane&15
        const unsigned s2 = ((unsigned)(lp & 7)) << 4;
        const int c0 = wv * 32 + lrow;
        *(float*)(sH + lp * 512 + (((unsigned)(c0 * 4)) ^ s2)) = acc[pth][0][r];
        *(float*)(sH + lp * 512 + (((unsigned)((c0 + 16) * 4)) ^ s2)) = acc[pth][1][r];
      }
    }
    __syncthreads();  // transposed f32 rows visible to all waves

    // epilogue for this pair's 32 points
#pragma unroll
    for (int it = 0; it < 4; ++it) {
      const int p = pg2 * 32 + it * 8 + (tid >> 5);
      const int c4g = tid & 31;
      const unsigned boff =
          (unsigned)(p * 512) + (((unsigned)(c4g * 16)) ^ (((unsigned)(p & 7)) << 4));
      const v4f t = *(const v4f*)(sH + boff);
      const u64 o8 = sOff8[p];
      const float4 w = sWl[p];
      const float4 bias = *(const float4*)(b2 + c4g * 4);
      float rx = t[0] + bias.x, ry = t[1] + bias.y, rz = t[2] + bias.z, rw = t[3] + bias.w;
      {
        const float4 f = *(const float4*)(featc + (size_t)(unsigned)(o8 & 0xFFFFu) * CC + c4g * 4);
        rx += w.x * f.x; ry += w.x * f.y; rz += w.x * f.z; rw += w.x * f.w;
      }
      {
        const float4 f =
            *(const float4*)(featc + (size_t)(unsigned)((o8 >> 16) & 0xFFFFu) * CC + c4g * 4);
        rx += w.y * f.x; ry += w.y * f.y; rz += w.y * f.z; rw += w.y * f.w;
      }
      {
        const float4 f =
            *(const float4*)(featc + (size_t)(unsigned)((o8 >> 32) & 0xFFFFu) * CC + c4g * 4);
        rx += w.z * f.x; ry += w.z * f.y; rz += w.z * f.z; rw += w.z * f.w;
      }
      {
        const float4 f =
            *(const float4*)(featc + (size_t)(unsigned)((o8 >> 48) & 0xFFFFu) * CC + c4g * 4);
        rx += w.w * f.x; ry += w.w * f.y; rz += w.w * f.z; rw += w.w * f.w;
      }
      *(float4*)(out + (size_t)(gp0 + p) * CC + c4g * 4) = make_float4(rx, ry, rz, rw);
    }
  }
}

// ---------------- last-resort fallback (no ws): fused fp32 kernel ----------------
__global__ __launch_bounds__(128) void gauss_fb(
    const float* __restrict__ means3D, const float* __restrict__ feat,
    const float* __restrict__ dvec, const float* __restrict__ cov3D,
    const float* __restrict__ l2i, const float* __restrict__ W1,
    const float* __restrict__ b1, const float* __restrict__ W2,
    const float* __restrict__ b2, float* __restrict__ out) {
  const int l = blockIdx.x;
  const int bn = blockIdx.y;
  const int tid = threadIdx.x;
  __shared__ float sH[P2][HID];
  __shared__ float sPn[P2][3];
  __shared__ float sW[P2][4];
  __shared__ int sOff[P2][4];
  if (tid < P2) {
    const int p = tid;
    const size_t base3 = ((size_t)bn * LL + l) * 3;
    const float m0 = means3D[base3 + 0], m1 = means3D[base3 + 1], m2 = means3D[base3 + 2];
    const float d0 = dvec[base3 + 0], d1 = dvec[base3 + 1], d2 = dvec[base3 + 2];
    const float* cv = cov3D + ((size_t)bn * LL + l) * 9;
    const float q = d0 * (cv[0] * d0 + cv[1] * d1 + cv[2] * d2) +
                    d1 * (cv[3] * d0 + cv[4] * d1 + cv[5] * d2) +
                    d2 * (cv[6] * d0 + cv[7] * d1 + cv[8] * d2);
    const float s = sqrtf(q);
    const int k = p >> 2, j = p & 3;
    const float a = (-1.5f + 0.75f * (float)k) * s;
    const float tt = -0.5f + (1.0f / 3.0f) * (float)j;
    const float px = m0 + a * d0 + tt * d1;
    const float py = m1 + a * d1 - tt * d0;
    const float pz = m2 + a * d2;
    const float* M = l2i + (size_t)bn * 16;
    const float cx = M[0] * px + M[1] * py + M[2] * pz + M[3];
    const float cy = M[4] * px + M[5] * py + M[6] * pz + M[7];
    const float cz = M[8] * px + M[9] * py + M[10] * pz + M[11];
    const float homo = fmaxf(cz, 1e-6f);
    const float u = cx / homo;
    const float v = cy / homo;
    float* camo = out + OUT_CAM_OFF + (((size_t)bn * LL + l) * P2 + p) * 2;
    camo[0] = u;
    camo[1] = v;
    float* ptso = out + OUT_PTS_OFF + (((size_t)bn * LL + l) * P2 + p) * 3;
    ptso[0] = px;
    ptso[1] = py;
    ptso[2] = pz;
    const float x = u * 0.125f - 0.5f;
    const float y = v * 0.125f - 0.5f;
    const float x0f = floorf(x), y0f = floorf(y);
    const float wx = x - x0f, wy = y - y0f;
    const bool vx0 = (x0f >= 0.f) && (x0f < (float)WG);
    const bool vx1 = (x0f + 1.f >= 0.f) && (x0f + 1.f < (float)WG);
    const bool vy0 = (y0f >= 0.f) && (y0f < (float)HG);
    const bool vy1 = (y0f + 1.f >= 0.f) && (y0f + 1.f < (float)HG);
    const int ix0 = (int)fminf(fmaxf(x0f, 0.f), (float)(WG - 1));
    const int ix1 = (int)fminf(fmaxf(x0f + 1.f, 0.f), (float)(WG - 1));
    const int iy0 = (int)fminf(fmaxf(y0f, 0.f), (float)(HG - 1));
    const int iy1 = (int)fminf(fmaxf(y0f + 1.f, 0.f), (float)(HG - 1));
    sOff[p][0] = iy0 * WG + ix0;
    sOff[p][1] = iy0 * WG + ix1;
    sOff[p][2] = iy1 * WG + ix0;
    sOff[p][3] = iy1 * WG + ix1;
    sW[p][0] = (vx0 && vy0) ? (1.f - wx) * (1.f - wy) : 0.f;
    sW[p][1] = (vx1 && vy0) ? wx * (1.f - wy) : 0.f;
    sW[p][2] = (vx0 && vy1) ? (1.f - wx) * wy : 0.f;
    sW[p][3] = (vx1 && vy1) ? wx * wy : 0.f;
    sPn[p][0] = fminf(fmaxf((px + 50.f) * 0.01f, 0.f), 1.f);
    sPn[p][1] = fminf(fmaxf((py + 50.f) * 0.01f, 0.f), 1.f);
    sPn[p][2] = fminf(fmaxf((pz + 4.f) * 0.125f, 0.f), 1.f);
  }
  __syncthreads();
  for (int u0 = tid; u0 < P2 * HID; u0 += 128) {
    const int p = u0 >> 8;
    const int h = u0 & (HID - 1);
    const float v = b1[h] + sPn[p][0] * W1[h] + sPn[p][1] * W1[HID + h] + sPn[p][2] * W1[2 * HID + h];
    sH[p][h] = fmaxf(v, 0.f);
  }
  __syncthreads();
  const int pg = tid >> 5;
  const int c0 = (tid & 31) * 4;
  const int pbase = pg * 5;
  float acc[5][4];
#pragma unroll
  for (int i = 0; i < 5; ++i)
#pragma unroll
    for (int j2 = 0; j2 < 4; ++j2) acc[i][j2] = 0.f;
  for (int h = 0; h < HID; h += 4) {
    const float4 w0 = *(const float4*)(W2 + (size_t)(h + 0) * CC + c0);
    const float4 w1 = *(const float4*)(W2 + (size_t)(h + 1) * CC + c0);
    const float4 w2 = *(const float4*)(W2 + (size_t)(h + 2) * CC + c0);
    const float4 w3 = *(const float4*)(W2 + (size_t)(h + 3) * CC + c0);
#pragma unroll
    for (int i = 0; i < 5; ++i) {
      const float4 hv = *(const float4*)(&sH[pbase + i][h]);
      acc[i][0] += hv.x * w0.x + hv.y * w1.x + hv.z * w2.x + hv.w * w3.x;
      acc[i][1] += hv.x * w0.y + hv.y * w1.y + hv.z * w2.y + hv.w * w3.y;
      acc[i][2] += hv.x * w0.z + hv.y * w1.z + hv.z * w2.z + hv.w * w3.z;
      acc[i][3] += hv.x * w0.w + hv.y * w1.w + hv.z * w2.w + hv.w * w3.w;
    }
  }
  const float4 bias = *(const float4*)(b2 + c0);
  const float* fbase = feat + (size_t)bn * CC * LL;
#pragma unroll
  for (int i = 0; i < 5; ++i) {
    const int p = pbase + i;
    float4 r;
    r.x = acc[i][0] + bias.x;
    r.y = acc[i][1] + bias.y;
    r.z = acc[i][2] + bias.z;
    r.w = acc[i][3] + bias.w;
#pragma unroll
    for (int corner = 0; corner < 4; ++corner) {
      const float w = sW[p][corner];
      const int off = sOff[p][corner];
      r.x += w * fbase[(size_t)(c0 + 0) * LL + off];
      r.y += w * fbase[(size_t)(c0 + 1) * LL + off];
      r.z += w * fbase[(size_t)(c0 + 2) * LL + off];
      r.w += w * fbase[(size_t)(c0 + 3) * LL + off];
    }
    *(float4*)(out + (((size_t)bn * LL + l) * P2 + p) * CC + c0) = r;
  }
}

extern "C" void kernel_launch(void* const* d_in, const int* in_sizes, int n_in,
                              void* d_out, int out_size, void* d_ws, size_t ws_size,
                              hipStream_t stream) {
  const float* means3D = (const float*)d_in[0];
  const float* img = (const float*)d_in[1];
  const float* dvec = (const float*)d_in[2];
  const float* cov3D = (const float*)d_in[3];
  const float* l2i = (const float*)d_in[4];
  const float* W1 = (const float*)d_in[5];
  const float* b1 = (const float*)d_in[6];
  const float* W2 = (const float*)d_in[7];
  const float* b2 = (const float*)d_in[8];
  float* out = (float*)d_out;

  const size_t w2bf_bytes = 65536;
  const size_t tbytes = (size_t)BN * LL * CC * sizeof(float);  // 10321920

  if (ws_size >= w2bf_bytes + tbytes) {
    unsigned short* W2bf = (unsigned short*)d_ws;
    float* featT = (float*)((char*)d_ws + w2bf_bytes);
    hipLaunchKernelGGL(prep_k, dim3(648 + 16), dim3(256), 0, stream, img, featT, W2, W2bf);
    hipLaunchKernelGGL(geom_k, dim3(NPTS / 256), dim3(256), 0, stream, means3D, dvec, cov3D,
                       l2i, out);
    hipLaunchKernelGGL(gemm_k, dim3(NWG), dim3(256), 0, stream, featT, W1, b1, W2bf, b2, out);
  } else {
    hipLaunchKernelGGL(gauss_fb, dim3(LL, BN), dim3(128), 0, stream, means3D, img, dvec, cov3D,
                       l2i, W1, b1, W2, b2, out);
  }
}

// Round 11
// 157.410 us; speedup vs baseline: 2.9196x; 2.9196x over previous
//
#include <hip/hip_runtime.h>
#include <hip/hip_bf16.h>
#include <math.h>

#define BN 12
#define HG 28
#define WG 60
#define LL 1680      // HG*WG
#define CC 128
#define P2 20
#define HID 256
#define NPTS (BN * LL * P2)  // 403200
#define NPB 64               // points per block in gemm kernel (R8 validated)
#define NWG (NPTS / NPB)     // 6300

static constexpr size_t OUT_CAM_OFF = (size_t)BN * LL * P2 * CC;              // 51609600
static constexpr size_t OUT_PTS_OFF = OUT_CAM_OFF + (size_t)BN * LL * P2 * 2; // 52416000

typedef short v8s __attribute__((ext_vector_type(8)));
typedef float v4f __attribute__((ext_vector_type(4)));
typedef unsigned long long u64;

__device__ __forceinline__ unsigned short f2bf(float f) {
  unsigned x = __float_as_uint(f);
  unsigned r = (x + 0x7FFFu + ((x >> 16) & 1u)) >> 16;
  return (unsigned short)r;
}

// ---------------- prep: transpose img (BN,C,L)->(BN,L,C) f32  ||  pack W2 ----------------
// Validated R7/R8 form.
__global__ __launch_bounds__(256) void prep_k(const float* __restrict__ img,
                                              float* __restrict__ featT,
                                              const float* __restrict__ W2,
                                              unsigned short* __restrict__ W2bf) {
  const int b = blockIdx.x;
  const int t = threadIdx.x;
  if (b < 648) {
    __shared__ float tile[64][65];
    const int bz = b / 54;         // bn
    const int rem = b - bz * 54;
    const int by = rem / 27;       // c-tile
    const int bx = rem - by * 27;  // l-tile
    const int c0 = by * 64;
    const int l0 = bx * 64;
    {
      const int lx = t & 63;
      const int cy = t >> 6;
#pragma unroll
      for (int i = 0; i < 64; i += 4) {
        const int c = c0 + cy + i;
        const int l = l0 + lx;
        float v = 0.f;
        if (l < LL) v = img[((size_t)bz * CC + c) * LL + l];
        tile[cy + i][lx] = v;
      }
    }
    __syncthreads();
    {
      const int cx = t & 63;
      const int ly = t >> 6;
#pragma unroll
      for (int i = 0; i < 64; i += 4) {
        const int l = l0 + ly + i;
        const int c = c0 + cx;
        if (l < LL) featT[((size_t)bz * LL + l) * CC + c] = tile[cx][ly + i];
      }
    }
  } else {
    const int u = (b - 648) * 256 + t;
    if (u < 4096) {
      const int lane = u & 63;
      const int ks = (u >> 6) & 7;
      const int cg = u >> 9;
      const int col = cg * 16 + (lane & 15);
      const int kb = ks * 32 + (lane >> 4) * 8;
      v8s r;
#pragma unroll
      for (int e = 0; e < 8; ++e) r[e] = (short)f2bf(W2[(size_t)(kb + e) * CC + col]);
      *(v8s*)(W2bf + (size_t)u * 8) = r;
    }
  }
}

// ---------------- kernel A: geometry -> cam/pts outputs ONLY ----------------
// Projection math FROZEN (passing R3/R5-R9). cam = cx/homo amplifies contraction-order noise
// near the 1e-6 clamp ~1e6x (R4's 1.6e8-scale failure mode); keep byte-identical, own kernel.
__global__ __launch_bounds__(256) void geom_k(const float* __restrict__ means3D,
                                              const float* __restrict__ dvec,
                                              const float* __restrict__ cov3D,
                                              const float* __restrict__ l2i,
                                              float* __restrict__ out) {
  const int pid = blockIdx.x * 256 + threadIdx.x;
  if (pid >= NPTS) return;
  const unsigned qg = (unsigned)pid / P2;
  const int p = pid - (int)qg * P2;
  const unsigned bn = qg / LL;

  const size_t base3 = (size_t)qg * 3;
  const float m0 = means3D[base3 + 0], m1 = means3D[base3 + 1], m2 = means3D[base3 + 2];
  const float d0 = dvec[base3 + 0], d1 = dvec[base3 + 1], d2 = dvec[base3 + 2];
  const float* cv = cov3D + (size_t)qg * 9;
  const float q = d0 * (cv[0] * d0 + cv[1] * d1 + cv[2] * d2) +
                  d1 * (cv[3] * d0 + cv[4] * d1 + cv[5] * d2) +
                  d2 * (cv[6] * d0 + cv[7] * d1 + cv[8] * d2);
  const float s = sqrtf(q);
  const int k = p >> 2, j = p & 3;
  const float a = (-1.5f + 0.75f * (float)k) * s;     // lin5[k]*sqrt(q)
  const float tt = -0.5f + (1.0f / 3.0f) * (float)j;  // linP[j]
  const float px = m0 + a * d0 + tt * d1;             // orth=(d1,-d0,0)
  const float py = m1 + a * d1 - tt * d0;
  const float pz = m2 + a * d2;
  const float* M = l2i + (size_t)bn * 16;
  const float cx = M[0] * px + M[1] * py + M[2] * pz + M[3];
  const float cy = M[4] * px + M[5] * py + M[6] * pz + M[7];
  const float cz = M[8] * px + M[9] * py + M[10] * pz + M[11];
  const float homo = fmaxf(cz, 1e-6f);
  const float u = cx / homo;
  const float v = cy / homo;

  *(float2*)(out + OUT_CAM_OFF + (size_t)pid * 2) = make_float2(u, v);
  float* ptso = out + OUT_PTS_OFF + (size_t)pid * 3;
  ptso[0] = px;
  ptso[1] = py;
  ptso[2] = pz;
}

// ---------------- kernel B: MLP via MFMA + bilinear gather + coalesced write ----------------
// Exact R8 structure (79.6 us validated). R11's ONE change: feats stores are NONTEMPORAL
// (no L2 allocate) so the 206 MB store stream stops evicting the 10.3 MB featT gather
// working set from L2. Values/order unchanged -> canary must stay 262144.0.
__global__ __launch_bounds__(256, 4) void gemm_k(
    const float* __restrict__ featT,  // (BN,L,C)
    const float* __restrict__ W1,
    const float* __restrict__ b1,
    const unsigned short* __restrict__ W2bf,
    const float* __restrict__ b2,
    float* __restrict__ out) {
  const int tid = threadIdx.x;
  const int wgid = blockIdx.x;
  const int gp0 = wgid * NPB;
  const int bn = wgid / 525;  // 33600 points per bn / 64; blocks never span bn

  __shared__ __align__(16) char sH[NPB * 512];
  __shared__ u64 sOff8[NPB];
  __shared__ float4 sWl[NPB];
  __shared__ float4 sPnl[NPB];

  const int wv = tid >> 6;
  const int lane = tid & 63;
  const int lrow = lane & 15;
  const int g = lane >> 4;

  // B-fragments for this wave's 32 channels (issued early; latency hides under staging)
  v8s fb0[8], fb1[8];
#pragma unroll
  for (int ks = 0; ks < 8; ++ks) {
    fb0[ks] = *(const v8s*)(W2bf + (size_t)(((wv * 2 + 0) * 8 + ks) * 64 + lane) * 8);
    fb1[ks] = *(const v8s*)(W2bf + (size_t)(((wv * 2 + 1) * 8 + ks) * 64 + lane) * 8);
  }

  // W1/b1 slice: loaded ONCE (loop-invariant per thread)
  const int h4 = (tid & 63) * 4;
  const int pw = tid >> 6;
  const float4 a0 = *(const float4*)(W1 + h4);
  const float4 a1 = *(const float4*)(W1 + HID + h4);
  const float4 a2 = *(const float4*)(W1 + 2 * HID + h4);
  const float4 bb = *(const float4*)(b1 + h4);

  // stage: read back cam/pts for this block's 64 points, derive bilinear records + pn
  if (tid < NPB) {
    const int pid = gp0 + tid;
    const float2 cm = *(const float2*)(out + OUT_CAM_OFF + (size_t)pid * 2);
    const float u = cm.x, v = cm.y;
    const float* ptso = out + OUT_PTS_OFF + (size_t)pid * 3;
    const float px = ptso[0], py = ptso[1], pz = ptso[2];

    const float x = u * 0.125f - 0.5f;
    const float y = v * 0.125f - 0.5f;
    const float x0f = floorf(x), y0f = floorf(y);
    const float wx = x - x0f, wy = y - y0f;
    const bool vx0 = (x0f >= 0.f) && (x0f < (float)WG);
    const bool vx1 = (x0f + 1.f >= 0.f) && (x0f + 1.f < (float)WG);
    const bool vy0 = (y0f >= 0.f) && (y0f < (float)HG);
    const bool vy1 = (y0f + 1.f >= 0.f) && (y0f + 1.f < (float)HG);
    const unsigned ix0 = (unsigned)(int)fminf(fmaxf(x0f, 0.f), (float)(WG - 1));
    const unsigned ix1 = (unsigned)(int)fminf(fmaxf(x0f + 1.f, 0.f), (float)(WG - 1));
    const unsigned iy0 = (unsigned)(int)fminf(fmaxf(y0f, 0.f), (float)(HG - 1));
    const unsigned iy1 = (unsigned)(int)fminf(fmaxf(y0f + 1.f, 0.f), (float)(HG - 1));
    sOff8[tid] = (u64)(iy0 * WG + ix0) | ((u64)(iy0 * WG + ix1) << 16) |
                 ((u64)(iy1 * WG + ix0) << 32) | ((u64)(iy1 * WG + ix1) << 48);
    sWl[tid] = make_float4((vx0 && vy0) ? (1.f - wx) * (1.f - wy) : 0.f,
                           (vx1 && vy0) ? wx * (1.f - wy) : 0.f,
                           (vx0 && vy1) ? (1.f - wx) * wy : 0.f,
                           (vx1 && vy1) ? wx * wy : 0.f);
    sPnl[tid] = make_float4(fminf(fmaxf((px + 50.f) * 0.01f, 0.f), 1.f),
                            fminf(fmaxf((py + 50.f) * 0.01f, 0.f), 1.f),
                            fminf(fmaxf((pz + 4.f) * 0.125f, 0.f), 1.f), 0.f);
  }
  __syncthreads();

  // phase A: H[64][256] = relu(pn @ W1 + b1) -> bf16 LDS (swizzled), b64 writes
#pragma unroll
  for (int it = 0; it < NPB / 4; ++it) {
    const int p = it * 4 + pw;
    const float4 pn = sPnl[p];
    const float v0 = fmaxf(bb.x + pn.x * a0.x + pn.y * a1.x + pn.z * a2.x, 0.f);
    const float v1 = fmaxf(bb.y + pn.x * a0.y + pn.y * a1.y + pn.z * a2.y, 0.f);
    const float v2 = fmaxf(bb.z + pn.x * a0.z + pn.y * a1.z + pn.z * a2.z, 0.f);
    const float v3 = fmaxf(bb.w + pn.x * a0.w + pn.y * a1.w + pn.z * a2.w, 0.f);
    __hip_bfloat162 plo = __float22bfloat162_rn(make_float2(v0, v1));
    __hip_bfloat162 phi = __float22bfloat162_rn(make_float2(v2, v3));
    const unsigned ulo = *reinterpret_cast<const unsigned*>(&plo);
    const unsigned uhi = *reinterpret_cast<const unsigned*>(&phi);
    const u64 pk = (u64)ulo | ((u64)uhi << 32);
    *(u64*)(sH + p * 512 + (((unsigned)(h4 * 2)) ^ (((unsigned)(p & 7)) << 4))) = pk;
  }
  __syncthreads();

  const float* featc = featT + (size_t)bn * (LL * CC);

  // phase B + interleaved epilogue: per pair {0,1},{2,3}:
  // MFMA both -> bar -> transpose both -> bar -> epilogue of this pair's 32 points
#pragma unroll
  for (int pg2 = 0; pg2 < 2; ++pg2) {
    v4f acc[2][2];
#pragma unroll
    for (int i = 0; i < 2; ++i)
#pragma unroll
      for (int c = 0; c < 2; ++c) acc[i][c] = (v4f){0.f, 0.f, 0.f, 0.f};

#pragma unroll
    for (int pth = 0; pth < 2; ++pth) {
      const int pt = pg2 * 2 + pth;
      const int arow = pt * 16 + lrow;
      const unsigned swz = ((unsigned)(arow & 7)) << 4;
      v8s fa[8];
#pragma unroll
      for (int ks = 0; ks < 8; ++ks)
        fa[ks] = *(const v8s*)(sH + arow * 512 + (((unsigned)(ks * 64 + g * 16)) ^ swz));
#pragma unroll
      for (int ks = 0; ks < 8; ++ks)
        acc[pth][0] = __builtin_amdgcn_mfma_f32_16x16x32_bf16(fa[ks], fb0[ks], acc[pth][0], 0, 0, 0);
#pragma unroll
      for (int ks = 0; ks < 8; ++ks)
        acc[pth][1] = __builtin_amdgcn_mfma_f32_16x16x32_bf16(fa[ks], fb1[ks], acc[pth][1], 0, 0, 0);
    }
    __syncthreads();  // all waves done reading this pair's bf16 rows
#pragma unroll
    for (int pth = 0; pth < 2; ++pth) {
      const int pt = pg2 * 2 + pth;
#pragma unroll
      for (int r = 0; r < 4; ++r) {
        const int lp = pt * 16 + g * 4 + r;  // C/D: row=(lane>>4)*4+r, col=lane&15
        const unsigned s2 = ((unsigned)(lp & 7)) << 4;
        const int c0 = wv * 32 + lrow;
        *(float*)(sH + lp * 512 + (((unsigned)(c0 * 4)) ^ s2)) = acc[pth][0][r];
        *(float*)(sH + lp * 512 + (((unsigned)((c0 + 16) * 4)) ^ s2)) = acc[pth][1][r];
      }
    }
    __syncthreads();  // transposed f32 rows of this pair visible to all waves

    // epilogue for this pair's 32 points (rows pg2*32..pg2*32+31); next pair's MFMA
    // reads rows (1-pg2)*32.. which this phase never touches -> no extra barrier needed.
#pragma unroll
    for (int it = 0; it < 4; ++it) {
      const int p = pg2 * 32 + it * 8 + (tid >> 5);
      const int c4g = tid & 31;
      const unsigned boff =
          (unsigned)(p * 512) + (((unsigned)(c4g * 16)) ^ (((unsigned)(p & 7)) << 4));
      const v4f t = *(const v4f*)(sH + boff);
      const u64 o8 = sOff8[p];
      const float4 w = sWl[p];
      const float4 bias = *(const float4*)(b2 + c4g * 4);
      float rx = t[0] + bias.x, ry = t[1] + bias.y, rz = t[2] + bias.z, rw = t[3] + bias.w;
      {
        const float4 f = *(const float4*)(featc + (size_t)(unsigned)(o8 & 0xFFFFu) * CC + c4g * 4);
        rx += w.x * f.x; ry += w.x * f.y; rz += w.x * f.z; rw += w.x * f.w;
      }
      {
        const float4 f =
            *(const float4*)(featc + (size_t)(unsigned)((o8 >> 16) & 0xFFFFu) * CC + c4g * 4);
        rx += w.y * f.x; ry += w.y * f.y; rz += w.y * f.z; rw += w.y * f.w;
      }
      {
        const float4 f =
            *(const float4*)(featc + (size_t)(unsigned)((o8 >> 32) & 0xFFFFu) * CC + c4g * 4);
        rx += w.z * f.x; ry += w.z * f.y; rz += w.z * f.z; rw += w.z * f.w;
      }
      {
        const float4 f =
            *(const float4*)(featc + (size_t)(unsigned)((o8 >> 48) & 0xFFFFu) * CC + c4g * 4);
        rx += w.w * f.x; ry += w.w * f.y; rz += w.w * f.z; rw += w.w * f.w;
      }
      v4f res;
      res[0] = rx; res[1] = ry; res[2] = rz; res[3] = rw;
      __builtin_nontemporal_store(res, (v4f*)(out + (size_t)(gp0 + p) * CC + c4g * 4));
    }
  }
}

// ---------------- last-resort fallback (no ws): fused fp32 kernel ----------------
__global__ __launch_bounds__(128) void gauss_fb(
    const float* __restrict__ means3D, const float* __restrict__ feat,
    const float* __restrict__ dvec, const float* __restrict__ cov3D,
    const float* __restrict__ l2i, const float* __restrict__ W1,
    const float* __restrict__ b1, const float* __restrict__ W2,
    const float* __restrict__ b2, float* __restrict__ out) {
  const int l = blockIdx.x;
  const int bn = blockIdx.y;
  const int tid = threadIdx.x;
  __shared__ float sH[P2][HID];
  __shared__ float sPn[P2][3];
  __shared__ float sW[P2][4];
  __shared__ int sOff[P2][4];
  if (tid < P2) {
    const int p = tid;
    const size_t base3 = ((size_t)bn * LL + l) * 3;
    const float m0 = means3D[base3 + 0], m1 = means3D[base3 + 1], m2 = means3D[base3 + 2];
    const float d0 = dvec[base3 + 0], d1 = dvec[base3 + 1], d2 = dvec[base3 + 2];
    const float* cv = cov3D + ((size_t)bn * LL + l) * 9;
    const float q = d0 * (cv[0] * d0 + cv[1] * d1 + cv[2] * d2) +
                    d1 * (cv[3] * d0 + cv[4] * d1 + cv[5] * d2) +
                    d2 * (cv[6] * d0 + cv[7] * d1 + cv[8] * d2);
    const float s = sqrtf(q);
    const int k = p >> 2, j = p & 3;
    const float a = (-1.5f + 0.75f * (float)k) * s;
    const float tt = -0.5f + (1.0f / 3.0f) * (float)j;
    const float px = m0 + a * d0 + tt * d1;
    const float py = m1 + a * d1 - tt * d0;
    const float pz = m2 + a * d2;
    const float* M = l2i + (size_t)bn * 16;
    const float cx = M[0] * px + M[1] * py + M[2] * pz + M[3];
    const float cy = M[4] * px + M[5] * py + M[6] * pz + M[7];
    const float cz = M[8] * px + M[9] * py + M[10] * pz + M[11];
    const float homo = fmaxf(cz, 1e-6f);
    const float u = cx / homo;
    const float v = cy / homo;
    float* camo = out + OUT_CAM_OFF + (((size_t)bn * LL + l) * P2 + p) * 2;
    camo[0] = u;
    camo[1] = v;
    float* ptso = out + OUT_PTS_OFF + (((size_t)bn * LL + l) * P2 + p) * 3;
    ptso[0] = px;
    ptso[1] = py;
    ptso[2] = pz;
    const float x = u * 0.125f - 0.5f;
    const float y = v * 0.125f - 0.5f;
    const float x0f = floorf(x), y0f = floorf(y);
    const float wx = x - x0f, wy = y - y0f;
    const bool vx0 = (x0f >= 0.f) && (x0f < (float)WG);
    const bool vx1 = (x0f + 1.f >= 0.f) && (x0f + 1.f < (float)WG);
    const bool vy0 = (y0f >= 0.f) && (y0f < (float)HG);
    const bool vy1 = (y0f + 1.f >= 0.f) && (y0f + 1.f < (float)HG);
    const int ix0 = (int)fminf(fmaxf(x0f, 0.f), (float)(WG - 1));
    const int ix1 = (int)fminf(fmaxf(x0f + 1.f, 0.f), (float)(WG - 1));
    const int iy0 = (int)fminf(fmaxf(y0f, 0.f), (float)(HG - 1));
    const int iy1 = (int)fminf(fmaxf(y0f + 1.f, 0.f), (float)(HG - 1));
    sOff[p][0] = iy0 * WG + ix0;
    sOff[p][1] = iy0 * WG + ix1;
    sOff[p][2] = iy1 * WG + ix0;
    sOff[p][3] = iy1 * WG + ix1;
    sW[p][0] = (vx0 && vy0) ? (1.f - wx) * (1.f - wy) : 0.f;
    sW[p][1] = (vx1 && vy0) ? wx * (1.f - wy) : 0.f;
    sW[p][2] = (vx0 && vy1) ? (1.f - wx) * wy : 0.f;
    sW[p][3] = (vx1 && vy1) ? wx * wy : 0.f;
    sPn[p][0] = fminf(fmaxf((px + 50.f) * 0.01f, 0.f), 1.f);
    sPn[p][1] = fminf(fmaxf((py + 50.f) * 0.01f, 0.f), 1.f);
    sPn[p][2] = fminf(fmaxf((pz + 4.f) * 0.125f, 0.f), 1.f);
  }
  __syncthreads();
  for (int u0 = tid; u0 < P2 * HID; u0 += 128) {
    const int p = u0 >> 8;
    const int h = u0 & (HID - 1);
    const float v = b1[h] + sPn[p][0] * W1[h] + sPn[p][1] * W1[HID + h] + sPn[p][2] * W1[2 * HID + h];
    sH[p][h] = fmaxf(v, 0.f);
  }
  __syncthreads();
  const int pg = tid >> 5;
  const int c0 = (tid & 31) * 4;
  const int pbase = pg * 5;
  float acc[5][4];
#pragma unroll
  for (int i = 0; i < 5; ++i)
#pragma unroll
    for (int j2 = 0; j2 < 4; ++j2) acc[i][j2] = 0.f;
  for (int h = 0; h < HID; h += 4) {
    const float4 w0 = *(const float4*)(W2 + (size_t)(h + 0) * CC + c0);
    const float4 w1 = *(const float4*)(W2 + (size_t)(h + 1) * CC + c0);
    const float4 w2 = *(const float4*)(W2 + (size_t)(h + 2) * CC + c0);
    const float4 w3 = *(const float4*)(W2 + (size_t)(h + 3) * CC + c0);
#pragma unroll
    for (int i = 0; i < 5; ++i) {
      const float4 hv = *(const float4*)(&sH[pbase + i][h]);
      acc[i][0] += hv.x * w0.x + hv.y * w1.x + hv.z * w2.x + hv.w * w3.x;
      acc[i][1] += hv.x * w0.y + hv.y * w1.y + hv.z * w2.y + hv.w * w3.y;
      acc[i][2] += hv.x * w0.z + hv.y * w1.z + hv.z * w2.z + hv.w * w3.z;
      acc[i][3] += hv.x * w0.w + hv.y * w1.w + hv.z * w2.w + hv.w * w3.w;
    }
  }
  const float4 bias = *(const float4*)(b2 + c0);
  const float* fbase = feat + (size_t)bn * CC * LL;
#pragma unroll
  for (int i = 0; i < 5; ++i) {
    const int p = pbase + i;
    float4 r;
    r.x = acc[i][0] + bias.x;
    r.y = acc[i][1] + bias.y;
    r.z = acc[i][2] + bias.z;
    r.w = acc[i][3] + bias.w;
#pragma unroll
    for (int corner = 0; corner < 4; ++corner) {
      const float w = sW[p][corner];
      const int off = sOff[p][corner];
      r.x += w * fbase[(size_t)(c0 + 0) * LL + off];
      r.y += w * fbase[(size_t)(c0 + 1) * LL + off];
      r.z += w * fbase[(size_t)(c0 + 2) * LL + off];
      r.w += w * fbase[(size_t)(c0 + 3) * LL + off];
    }
    *(float4*)(out + (((size_t)bn * LL + l) * P2 + p) * CC + c0) = r;
  }
}

extern "C" void kernel_launch(void* const* d_in, const int* in_sizes, int n_in,
                              void* d_out, int out_size, void* d_ws, size_t ws_size,
                              hipStream_t stream) {
  const float* means3D = (const float*)d_in[0];
  const float* img = (const float*)d_in[1];
  const float* dvec = (const float*)d_in[2];
  const float* cov3D = (const float*)d_in[3];
  const float* l2i = (const float*)d_in[4];
  const float* W1 = (const float*)d_in[5];
  const float* b1 = (const float*)d_in[6];
  const float* W2 = (const float*)d_in[7];
  const float* b2 = (const float*)d_in[8];
  float* out = (float*)d_out;

  const size_t w2bf_bytes = 65536;
  const size_t tbytes = (size_t)BN * LL * CC * sizeof(float);  // 10321920

  if (ws_size >= w2bf_bytes + tbytes) {
    unsigned short* W2bf = (unsigned short*)d_ws;
    float* featT = (float*)((char*)d_ws + w2bf_bytes);
    hipLaunchKernelGGL(prep_k, dim3(648 + 16), dim3(256), 0, stream, img, featT, W2, W2bf);
    hipLaunchKernelGGL(geom_k, dim3(NPTS / 256), dim3(256), 0, stream, means3D, dvec, cov3D,
                       l2i, out);
    hipLaunchKernelGGL(gemm_k, dim3(NWG), dim3(256), 0, stream, featT, W1, b1, W2bf, b2, out);
  } else {
    hipLaunchKernelGGL(gauss_fb, dim3(LL, BN), dim3(128), 0, stream, means3D, img, dvec, cov3D,
                       l2i, W1, b1, W2, b2, out);
  }
}

// Round 12
// 80.339 us; speedup vs baseline: 5.7205x; 1.9593x over previous
//
#include <hip/hip_runtime.h>
#include <hip/hip_bf16.h>
#include <math.h>

#define BN 12
#define HG 28
#define WG 60
#define LL 1680      // HG*WG
#define CC 128
#define P2 20
#define HID 256
#define NPTS (BN * LL * P2)  // 403200
#define NPB 64               // points per block in gemm kernel
#define NWG (NPTS / NPB)     // 6300

static constexpr size_t OUT_CAM_OFF = (size_t)BN * LL * P2 * CC;              // 51609600
static constexpr size_t OUT_PTS_OFF = OUT_CAM_OFF + (size_t)BN * LL * P2 * 2; // 52416000

typedef short v8s __attribute__((ext_vector_type(8)));
typedef float v4f __attribute__((ext_vector_type(4)));
typedef unsigned long long u64;

__device__ __forceinline__ unsigned short f2bf(float f) {
  unsigned x = __float_as_uint(f);
  unsigned r = (x + 0x7FFFu + ((x >> 16) & 1u)) >> 16;
  return (unsigned short)r;
}

// ---------------- prep: transpose img (BN,C,L)->(BN,L,C)  ||  pack W2 to bf16 frags ---------
// Validated in R7/R8. blocks 0..647: transpose tiles. blocks 648..663: W2 pack.
__global__ __launch_bounds__(256) void prep_k(const float* __restrict__ img,
                                              float* __restrict__ featT,
                                              const float* __restrict__ W2,
                                              unsigned short* __restrict__ W2bf) {
  const int b = blockIdx.x;
  const int t = threadIdx.x;
  if (b < 648) {
    __shared__ float tile[64][65];
    const int bz = b / 54;         // bn
    const int rem = b - bz * 54;
    const int by = rem / 27;       // c-tile
    const int bx = rem - by * 27;  // l-tile
    const int c0 = by * 64;
    const int l0 = bx * 64;
    {
      const int lx = t & 63;
      const int cy = t >> 6;
#pragma unroll
      for (int i = 0; i < 64; i += 4) {
        const int c = c0 + cy + i;
        const int l = l0 + lx;
        float v = 0.f;
        if (l < LL) v = img[((size_t)bz * CC + c) * LL + l];
        tile[cy + i][lx] = v;
      }
    }
    __syncthreads();
    {
      const int cx = t & 63;
      const int ly = t >> 6;
#pragma unroll
      for (int i = 0; i < 64; i += 4) {
        const int l = l0 + ly + i;
        const int c = c0 + cx;
        if (l < LL) featT[((size_t)bz * LL + l) * CC + c] = tile[cx][ly + i];
      }
    }
  } else {
    const int u = (b - 648) * 256 + t;
    if (u < 4096) {
      const int lane = u & 63;
      const int ks = (u >> 6) & 7;
      const int cg = u >> 9;
      const int col = cg * 16 + (lane & 15);
      const int kb = ks * 32 + (lane >> 4) * 8;
      v8s r;
#pragma unroll
      for (int e = 0; e < 8; ++e) r[e] = (short)f2bf(W2[(size_t)(kb + e) * CC + col]);
      *(v8s*)(W2bf + (size_t)u * 8) = r;
    }
  }
}

// ---------------- kernel A: geometry -> cam/pts outputs ONLY ----------------
// Projection math FROZEN (passing R3/R5-R12). cam = cx/homo amplifies contraction-order
// noise near the homo clamp ~1e6x; keep this expression tree byte-identical, own kernel.
__global__ __launch_bounds__(256) void geom_k(const float* __restrict__ means3D,
                                              const float* __restrict__ dvec,
                                              const float* __restrict__ cov3D,
                                              const float* __restrict__ l2i,
                                              float* __restrict__ out) {
  const int pid = blockIdx.x * 256 + threadIdx.x;
  if (pid >= NPTS) return;
  const unsigned qg = (unsigned)pid / P2;
  const int p = pid - (int)qg * P2;
  const unsigned bn = qg / LL;

  const size_t base3 = (size_t)qg * 3;
  const float m0 = means3D[base3 + 0], m1 = means3D[base3 + 1], m2 = means3D[base3 + 2];
  const float d0 = dvec[base3 + 0], d1 = dvec[base3 + 1], d2 = dvec[base3 + 2];
  const float* cv = cov3D + (size_t)qg * 9;
  const float q = d0 * (cv[0] * d0 + cv[1] * d1 + cv[2] * d2) +
                  d1 * (cv[3] * d0 + cv[4] * d1 + cv[5] * d2) +
                  d2 * (cv[6] * d0 + cv[7] * d1 + cv[8] * d2);
  const float s = sqrtf(q);
  const int k = p >> 2, j = p & 3;
  const float a = (-1.5f + 0.75f * (float)k) * s;     // lin5[k]*sqrt(q)
  const float tt = -0.5f + (1.0f / 3.0f) * (float)j;  // linP[j]
  const float px = m0 + a * d0 + tt * d1;             // orth=(d1,-d0,0)
  const float py = m1 + a * d1 - tt * d0;
  const float pz = m2 + a * d2;
  const float* M = l2i + (size_t)bn * 16;
  const float cx = M[0] * px + M[1] * py + M[2] * pz + M[3];
  const float cy = M[4] * px + M[5] * py + M[6] * pz + M[7];
  const float cz = M[8] * px + M[9] * py + M[10] * pz + M[11];
  const float homo = fmaxf(cz, 1e-6f);
  const float u = cx / homo;
  const float v = cy / homo;

  *(float2*)(out + OUT_CAM_OFF + (size_t)pid * 2) = make_float2(u, v);
  float* ptso = out + OUT_PTS_OFF + (size_t)pid * 3;
  ptso[0] = px;
  ptso[1] = py;
  ptso[2] = pz;
}

// ---------------- kernel B: MLP via MFMA + bilinear gather + coalesced write ----------------
// Exact R8 structure (79.6 us validated). R9 (bf16 featT), R10 (occupancy-6), R11
// (nontemporal stores) all regressed and are reverted.
__global__ __launch_bounds__(256, 4) void gemm_k(
    const float* __restrict__ featT,  // (BN,L,C)
    const float* __restrict__ W1,
    const float* __restrict__ b1,
    const unsigned short* __restrict__ W2bf,
    const float* __restrict__ b2,
    float* __restrict__ out) {
  const int tid = threadIdx.x;
  const int wgid = blockIdx.x;
  const int gp0 = wgid * NPB;
  const int bn = wgid / 525;  // 33600 points per bn / 64; blocks never span bn

  __shared__ __align__(16) char sH[NPB * 512];
  __shared__ u64 sOff8[NPB];
  __shared__ float4 sWl[NPB];
  __shared__ float4 sPnl[NPB];

  const int wv = tid >> 6;
  const int lane = tid & 63;
  const int lrow = lane & 15;
  const int g = lane >> 4;

  // B-fragments for this wave's 32 channels (issued early; latency hides under staging)
  v8s fb0[8], fb1[8];
#pragma unroll
  for (int ks = 0; ks < 8; ++ks) {
    fb0[ks] = *(const v8s*)(W2bf + (size_t)(((wv * 2 + 0) * 8 + ks) * 64 + lane) * 8);
    fb1[ks] = *(const v8s*)(W2bf + (size_t)(((wv * 2 + 1) * 8 + ks) * 64 + lane) * 8);
  }

  // W1/b1 slice: loaded ONCE (loop-invariant per thread)
  const int h4 = (tid & 63) * 4;
  const int pw = tid >> 6;
  const float4 a0 = *(const float4*)(W1 + h4);
  const float4 a1 = *(const float4*)(W1 + HID + h4);
  const float4 a2 = *(const float4*)(W1 + 2 * HID + h4);
  const float4 bb = *(const float4*)(b1 + h4);

  // stage: read back cam/pts for this block's 64 points, derive bilinear records + pn
  if (tid < NPB) {
    const int pid = gp0 + tid;
    const float2 cm = *(const float2*)(out + OUT_CAM_OFF + (size_t)pid * 2);
    const float u = cm.x, v = cm.y;
    const float* ptso = out + OUT_PTS_OFF + (size_t)pid * 3;
    const float px = ptso[0], py = ptso[1], pz = ptso[2];

    const float x = u * 0.125f - 0.5f;
    const float y = v * 0.125f - 0.5f;
    const float x0f = floorf(x), y0f = floorf(y);
    const float wx = x - x0f, wy = y - y0f;
    const bool vx0 = (x0f >= 0.f) && (x0f < (float)WG);
    const bool vx1 = (x0f + 1.f >= 0.f) && (x0f + 1.f < (float)WG);
    const bool vy0 = (y0f >= 0.f) && (y0f < (float)HG);
    const bool vy1 = (y0f + 1.f >= 0.f) && (y0f + 1.f < (float)HG);
    const unsigned ix0 = (unsigned)(int)fminf(fmaxf(x0f, 0.f), (float)(WG - 1));
    const unsigned ix1 = (unsigned)(int)fminf(fmaxf(x0f + 1.f, 0.f), (float)(WG - 1));
    const unsigned iy0 = (unsigned)(int)fminf(fmaxf(y0f, 0.f), (float)(HG - 1));
    const unsigned iy1 = (unsigned)(int)fminf(fmaxf(y0f + 1.f, 0.f), (float)(HG - 1));
    sOff8[tid] = (u64)(iy0 * WG + ix0) | ((u64)(iy0 * WG + ix1) << 16) |
                 ((u64)(iy1 * WG + ix0) << 32) | ((u64)(iy1 * WG + ix1) << 48);
    sWl[tid] = make_float4((vx0 && vy0) ? (1.f - wx) * (1.f - wy) : 0.f,
                           (vx1 && vy0) ? wx * (1.f - wy) : 0.f,
                           (vx0 && vy1) ? (1.f - wx) * wy : 0.f,
                           (vx1 && vy1) ? wx * wy : 0.f);
    sPnl[tid] = make_float4(fminf(fmaxf((px + 50.f) * 0.01f, 0.f), 1.f),
                            fminf(fmaxf((py + 50.f) * 0.01f, 0.f), 1.f),
                            fminf(fmaxf((pz + 4.f) * 0.125f, 0.f), 1.f), 0.f);
  }
  __syncthreads();

  // phase A: H[64][256] = relu(pn @ W1 + b1) -> bf16 LDS (swizzled), b64 writes
#pragma unroll
  for (int it = 0; it < NPB / 4; ++it) {
    const int p = it * 4 + pw;
    const float4 pn = sPnl[p];
    const float v0 = fmaxf(bb.x + pn.x * a0.x + pn.y * a1.x + pn.z * a2.x, 0.f);
    const float v1 = fmaxf(bb.y + pn.x * a0.y + pn.y * a1.y + pn.z * a2.y, 0.f);
    const float v2 = fmaxf(bb.z + pn.x * a0.z + pn.y * a1.z + pn.z * a2.z, 0.f);
    const float v3 = fmaxf(bb.w + pn.x * a0.w + pn.y * a1.w + pn.z * a2.w, 0.f);
    __hip_bfloat162 plo = __float22bfloat162_rn(make_float2(v0, v1));
    __hip_bfloat162 phi = __float22bfloat162_rn(make_float2(v2, v3));
    const unsigned ulo = *reinterpret_cast<const unsigned*>(&plo);
    const unsigned uhi = *reinterpret_cast<const unsigned*>(&phi);
    const u64 pk = (u64)ulo | ((u64)uhi << 32);
    *(u64*)(sH + p * 512 + (((unsigned)(h4 * 2)) ^ (((unsigned)(p & 7)) << 4))) = pk;
  }
  __syncthreads();

  const float* featc = featT + (size_t)bn * (LL * CC);

  // phase B + interleaved epilogue: per pair {0,1},{2,3}:
  // MFMA both -> bar -> transpose both -> bar -> epilogue of this pair's 32 points
#pragma unroll
  for (int pg2 = 0; pg2 < 2; ++pg2) {
    v4f acc[2][2];
#pragma unroll
    for (int i = 0; i < 2; ++i)
#pragma unroll
      for (int c = 0; c < 2; ++c) acc[i][c] = (v4f){0.f, 0.f, 0.f, 0.f};

#pragma unroll
    for (int pth = 0; pth < 2; ++pth) {
      const int pt = pg2 * 2 + pth;
      const int arow = pt * 16 + lrow;
      const unsigned swz = ((unsigned)(arow & 7)) << 4;
      v8s fa[8];
#pragma unroll
      for (int ks = 0; ks < 8; ++ks)
        fa[ks] = *(const v8s*)(sH + arow * 512 + (((unsigned)(ks * 64 + g * 16)) ^ swz));
#pragma unroll
      for (int ks = 0; ks < 8; ++ks)
        acc[pth][0] = __builtin_amdgcn_mfma_f32_16x16x32_bf16(fa[ks], fb0[ks], acc[pth][0], 0, 0, 0);
#pragma unroll
      for (int ks = 0; ks < 8; ++ks)
        acc[pth][1] = __builtin_amdgcn_mfma_f32_16x16x32_bf16(fa[ks], fb1[ks], acc[pth][1], 0, 0, 0);
    }
    __syncthreads();  // all waves done reading this pair's bf16 rows
#pragma unroll
    for (int pth = 0; pth < 2; ++pth) {
      const int pt = pg2 * 2 + pth;
#pragma unroll
      for (int r = 0; r < 4; ++r) {
        const int lp = pt * 16 + g * 4 + r;  // C/D: row=(lane>>4)*4+r, col=lane&15
        const unsigned s2 = ((unsigned)(lp & 7)) << 4;
        const int c0 = wv * 32 + lrow;
        *(float*)(sH + lp * 512 + (((unsigned)(c0 * 4)) ^ s2)) = acc[pth][0][r];
        *(float*)(sH + lp * 512 + (((unsigned)((c0 + 16) * 4)) ^ s2)) = acc[pth][1][r];
      }
    }
    __syncthreads();  // transposed f32 rows of this pair visible to all waves

    // epilogue for this pair's 32 points (rows pg2*32..pg2*32+31); next pair's MFMA
    // reads rows (1-pg2)*32.. which this phase never touches -> no extra barrier needed.
#pragma unroll
    for (int it = 0; it < 4; ++it) {
      const int p = pg2 * 32 + it * 8 + (tid >> 5);
      const int c4g = tid & 31;
      const unsigned boff =
          (unsigned)(p * 512) + (((unsigned)(c4g * 16)) ^ (((unsigned)(p & 7)) << 4));
      const v4f t = *(const v4f*)(sH + boff);
      const u64 o8 = sOff8[p];
      const float4 w = sWl[p];
      const float4 bias = *(const float4*)(b2 + c4g * 4);
      float rx = t[0] + bias.x, ry = t[1] + bias.y, rz = t[2] + bias.z, rw = t[3] + bias.w;
      {
        const float4 f = *(const float4*)(featc + (size_t)(unsigned)(o8 & 0xFFFFu) * CC + c4g * 4);
        rx += w.x * f.x; ry += w.x * f.y; rz += w.x * f.z; rw += w.x * f.w;
      }
      {
        const float4 f =
            *(const float4*)(featc + (size_t)(unsigned)((o8 >> 16) & 0xFFFFu) * CC + c4g * 4);
        rx += w.y * f.x; ry += w.y * f.y; rz += w.y * f.z; rw += w.y * f.w;
      }
      {
        const float4 f =
            *(const float4*)(featc + (size_t)(unsigned)((o8 >> 32) & 0xFFFFu) * CC + c4g * 4);
        rx += w.z * f.x; ry += w.z * f.y; rz += w.z * f.z; rw += w.z * f.w;
      }
      {
        const float4 f =
            *(const float4*)(featc + (size_t)(unsigned)((o8 >> 48) & 0xFFFFu) * CC + c4g * 4);
        rx += w.w * f.x; ry += w.w * f.y; rz += w.w * f.z; rw += w.w * f.w;
      }
      *(float4*)(out + (size_t)(gp0 + p) * CC + c4g * 4) = make_float4(rx, ry, rz, rw);
    }
  }
}

// ---------------- last-resort fallback (no ws): fused fp32 kernel ----------------
__global__ __launch_bounds__(128) void gauss_fb(
    const float* __restrict__ means3D, const float* __restrict__ feat,
    const float* __restrict__ dvec, const float* __restrict__ cov3D,
    const float* __restrict__ l2i, const float* __restrict__ W1,
    const float* __restrict__ b1, const float* __restrict__ W2,
    const float* __restrict__ b2, float* __restrict__ out) {
  const int l = blockIdx.x;
  const int bn = blockIdx.y;
  const int tid = threadIdx.x;
  __shared__ float sH[P2][HID];
  __shared__ float sPn[P2][3];
  __shared__ float sW[P2][4];
  __shared__ int sOff[P2][4];
  if (tid < P2) {
    const int p = tid;
    const size_t base3 = ((size_t)bn * LL + l) * 3;
    const float m0 = means3D[base3 + 0], m1 = means3D[base3 + 1], m2 = means3D[base3 + 2];
    const float d0 = dvec[base3 + 0], d1 = dvec[base3 + 1], d2 = dvec[base3 + 2];
    const float* cv = cov3D + ((size_t)bn * LL + l) * 9;
    const float q = d0 * (cv[0] * d0 + cv[1] * d1 + cv[2] * d2) +
                    d1 * (cv[3] * d0 + cv[4] * d1 + cv[5] * d2) +
                    d2 * (cv[6] * d0 + cv[7] * d1 + cv[8] * d2);
    const float s = sqrtf(q);
    const int k = p >> 2, j = p & 3;
    const float a = (-1.5f + 0.75f * (float)k) * s;
    const float tt = -0.5f + (1.0f / 3.0f) * (float)j;
    const float px = m0 + a * d0 + tt * d1;
    const float py = m1 + a * d1 - tt * d0;
    const float pz = m2 + a * d2;
    const float* M = l2i + (size_t)bn * 16;
    const float cx = M[0] * px + M[1] * py + M[2] * pz + M[3];
    const float cy = M[4] * px + M[5] * py + M[6] * pz + M[7];
    const float cz = M[8] * px + M[9] * py + M[10] * pz + M[11];
    const float homo = fmaxf(cz, 1e-6f);
    const float u = cx / homo;
    const float v = cy / homo;
    float* camo = out + OUT_CAM_OFF + (((size_t)bn * LL + l) * P2 + p) * 2;
    camo[0] = u;
    camo[1] = v;
    float* ptso = out + OUT_PTS_OFF + (((size_t)bn * LL + l) * P2 + p) * 3;
    ptso[0] = px;
    ptso[1] = py;
    ptso[2] = pz;
    const float x = u * 0.125f - 0.5f;
    const float y = v * 0.125f - 0.5f;
    const float x0f = floorf(x), y0f = floorf(y);
    const float wx = x - x0f, wy = y - y0f;
    const bool vx0 = (x0f >= 0.f) && (x0f < (float)WG);
    const bool vx1 = (x0f + 1.f >= 0.f) && (x0f + 1.f < (float)WG);
    const bool vy0 = (y0f >= 0.f) && (y0f < (float)HG);
    const bool vy1 = (y0f + 1.f >= 0.f) && (y0f + 1.f < (float)HG);
    const int ix0 = (int)fminf(fmaxf(x0f, 0.f), (float)(WG - 1));
    const int ix1 = (int)fminf(fmaxf(x0f + 1.f, 0.f), (float)(WG - 1));
    const int iy0 = (int)fminf(fmaxf(y0f, 0.f), (float)(HG - 1));
    const int iy1 = (int)fminf(fmaxf(y0f + 1.f, 0.f), (float)(HG - 1));
    sOff[p][0] = iy0 * WG + ix0;
    sOff[p][1] = iy0 * WG + ix1;
    sOff[p][2] = iy1 * WG + ix0;
    sOff[p][3] = iy1 * WG + ix1;
    sW[p][0] = (vx0 && vy0) ? (1.f - wx) * (1.f - wy) : 0.f;
    sW[p][1] = (vx1 && vy0) ? wx * (1.f - wy) : 0.f;
    sW[p][2] = (vx0 && vy1) ? (1.f - wx) * wy : 0.f;
    sW[p][3] = (vx1 && vy1) ? wx * wy : 0.f;
    sPn[p][0] = fminf(fmaxf((px + 50.f) * 0.01f, 0.f), 1.f);
    sPn[p][1] = fminf(fmaxf((py + 50.f) * 0.01f, 0.f), 1.f);
    sPn[p][2] = fminf(fmaxf((pz + 4.f) * 0.125f, 0.f), 1.f);
  }
  __syncthreads();
  for (int u0 = tid; u0 < P2 * HID; u0 += 128) {
    const int p = u0 >> 8;
    const int h = u0 & (HID - 1);
    const float v = b1[h] + sPn[p][0] * W1[h] + sPn[p][1] * W1[HID + h] + sPn[p][2] * W1[2 * HID + h];
    sH[p][h] = fmaxf(v, 0.f);
  }
  __syncthreads();
  const int pg = tid >> 5;
  const int c0 = (tid & 31) * 4;
  const int pbase = pg * 5;
  float acc[5][4];
#pragma unroll
  for (int i = 0; i < 5; ++i)
#pragma unroll
    for (int j2 = 0; j2 < 4; ++j2) acc[i][j2] = 0.f;
  for (int h = 0; h < HID; h += 4) {
    const float4 w0 = *(const float4*)(W2 + (size_t)(h + 0) * CC + c0);
    const float4 w1 = *(const float4*)(W2 + (size_t)(h + 1) * CC + c0);
    const float4 w2 = *(const float4*)(W2 + (size_t)(h + 2) * CC + c0);
    const float4 w3 = *(const float4*)(W2 + (size_t)(h + 3) * CC + c0);
#pragma unroll
    for (int i = 0; i < 5; ++i) {
      const float4 hv = *(const float4*)(&sH[pbase + i][h]);
      acc[i][0] += hv.x * w0.x + hv.y * w1.x + hv.z * w2.x + hv.w * w3.x;
      acc[i][1] += hv.x * w0.y + hv.y * w1.y + hv.z * w2.y + hv.w * w3.y;
      acc[i][2] += hv.x * w0.z + hv.y * w1.z + hv.z * w2.z + hv.w * w3.z;
      acc[i][3] += hv.x * w0.w + hv.y * w1.w + hv.z * w2.w + hv.w * w3.w;
    }
  }
  const float4 bias = *(const float4*)(b2 + c0);
  const float* fbase = feat + (size_t)bn * CC * LL;
#pragma unroll
  for (int i = 0; i < 5; ++i) {
    const int p = pbase + i;
    float4 r;
    r.x = acc[i][0] + bias.x;
    r.y = acc[i][1] + bias.y;
    r.z = acc[i][2] + bias.z;
    r.w = acc[i][3] + bias.w;
#pragma unroll
    for (int corner = 0; corner < 4; ++corner) {
      const float w = sW[p][corner];
      const int off = sOff[p][corner];
      r.x += w * fbase[(size_t)(c0 + 0) * LL + off];
      r.y += w * fbase[(size_t)(c0 + 1) * LL + off];
      r.z += w * fbase[(size_t)(c0 + 2) * LL + off];
      r.w += w * fbase[(size_t)(c0 + 3) * LL + off];
    }
    *(float4*)(out + (((size_t)bn * LL + l) * P2 + p) * CC + c0) = r;
  }
}

extern "C" void kernel_launch(void* const* d_in, const int* in_sizes, int n_in,
                              void* d_out, int out_size, void* d_ws, size_t ws_size,
                              hipStream_t stream) {
  const float* means3D = (const float*)d_in[0];
  const float* img = (const float*)d_in[1];
  const float* dvec = (const float*)d_in[2];
  const float* cov3D = (const float*)d_in[3];
  const float* l2i = (const float*)d_in[4];
  const float* W1 = (const float*)d_in[5];
  const float* b1 = (const float*)d_in[6];
  const float* W2 = (const float*)d_in[7];
  const float* b2 = (const float*)d_in[8];
  float* out = (float*)d_out;

  const size_t w2bf_bytes = 65536;
  const size_t tbytes = (size_t)BN * LL * CC * sizeof(float);  // 10321920

  if (ws_size >= w2bf_bytes + tbytes) {
    unsigned short* W2bf = (unsigned short*)d_ws;
    float* featT = (float*)((char*)d_ws + w2bf_bytes);
    hipLaunchKernelGGL(prep_k, dim3(648 + 16), dim3(256), 0, stream, img, featT, W2, W2bf);
    hipLaunchKernelGGL(geom_k, dim3(NPTS / 256), dim3(256), 0, stream, means3D, dvec, cov3D,
                       l2i, out);
    hipLaunchKernelGGL(gemm_k, dim3(NWG), dim3(256), 0, stream, featT, W1, b1, W2bf, b2, out);
  } else {
    hipLaunchKernelGGL(gauss_fb, dim3(LL, BN), dim3(128), 0, stream, means3D, img, dvec, cov3D,
                       l2i, W1, b1, W2, b2, out);
  }
}